// Round 15
// baseline (143.920 us; speedup 1.0000x reference)
//
#include <hip/hip_runtime.h>

// RecurrentCrossLinearAttention: N=16, S=4096, H=16, D=64, M=64, fp32.
// Round 15: DEEPEN the async pipeline (r14 was correct but queue-starved:
// ~25 KB in flight/CU -> ~1us latency tolerance -> HBM stuck at 2.5 TB/s
// with all pipes idle; r8/r12/r14 all converge ~105us at same depth).
//  - 16-row chunks (8 VMEM each), 4 LDS buffers/wave, issue 3 chunks
//    ahead, uniform s_waitcnt vmcnt(16): 24 KB in flight/wave, 96 KB/CU,
//    ~25 MB chip-wide (~4us tolerance at 6.3 TB/s).
//  - masks preloaded at prologue (16 GLOAD4) -> uniform vmcnt math.
//  - K=32 MFMA kept by chunk-pairing: each lane transforms its 8 frag
//    rows on its parity chunk (half-wave exec; same total work); frags
//    live in regs across one sub-iter. 4x-unrolled loop = static buffer
//    indices + parity (rule #20).
//  - NO barriers in partial kernel; per-wave partials -> d_ws (17 MB,
//    proven: r11/r12 WRITE_SIZE 16.6MB) + r9-proven reduce kernel.
// launch_bounds (256,1): cap 256 VGPR (law). Canary: WRITE ~21 MB.

#define S_LEN  4096
#define NHEAD  16
#define DDIM   64
#define MDIM   64
#define NWAVE  4
#define CH_S   16                 // s-rows per chunk (2 chunks = MFMA k)
#define NCHK   64                 // chunks per wave: 1024/16
#define PITCH  1024               // floats per s row (NHEAD*DDIM)
#define WS_ROW 4160               // floats per partial: 64*64 S + 64 z

#define OUT_SOFF  (16 * 16 * 64)
#define OUT_ZOFF  (OUT_SOFF + 16 * 16 * 64 * 64)

using short8 = __attribute__((ext_vector_type(8))) short;
using f32x4  = __attribute__((ext_vector_type(4))) float;
using uint4v = __attribute__((ext_vector_type(4))) unsigned int;

union FragCast { uint4v u; short8 s; };

typedef const __attribute__((address_space(1))) void gvoid_t;
typedef __attribute__((address_space(3))) void lvoid_t;

#define GLOAD16(dst, src) \
    __builtin_amdgcn_global_load_lds((gvoid_t*)(src), (lvoid_t*)(dst), 16, 0, 0)
#define GLOAD4(dst, src) \
    __builtin_amdgcn_global_load_lds((gvoid_t*)(src), (lvoid_t*)(dst), 4, 0, 0)
#define WAITVM(N) do { asm volatile("s_waitcnt vmcnt(" #N ")" ::: "memory"); \
                       __builtin_amdgcn_sched_barrier(0); } while (0)

__device__ __forceinline__ float elup1(float x) {
    // elu(x) + 1 = x+1 (x>0) else exp(x)
    return x > 0.0f ? x + 1.0f : __expf(x);
}

// pack two fp32 -> {lo=bf16(a), hi=bf16(b)} with round-to-nearest-even
__device__ __forceinline__ unsigned bfpack(float a, float b) {
    union { float f; unsigned u; } ca, cb;
    ca.f = a; cb.f = b;
    const unsigned ra = ca.u + 0x7FFFu + ((ca.u >> 16) & 1u);
    const unsigned rb = cb.u + 0x7FFFu + ((cb.u >> 16) & 1u);
    return (ra >> 16) | (rb & 0xFFFF0000u);
}

__global__ __launch_bounds__(256, 1)
void rcla_partial(const float* __restrict__ keys,
                  const float* __restrict__ values,
                  const float* __restrict__ kmask,
                  float* __restrict__ ws)
{
    __shared__ float Kbuf[NWAVE][4][CH_S * DDIM];  // 64 KB
    __shared__ float Vbuf[NWAVE][4][CH_S * DDIM];  // 64 KB
    __shared__ float maskL[NWAVE][1024];           // 16 KB

    const int t    = threadIdx.x;
    const int wave = t >> 6;                   // 0..3
    const int lane = t & 63;
    const int c16  = lane & 15;                // free index (m for A, d for B)
    const int g    = lane >> 4;                // k-group 0..3
    const int pair = blockIdx.x;               // n*16 + h
    const int nIdx = pair >> 4;
    const int hIdx = pair & 15;

    const int sWave = wave * (NCHK * CH_S);    // 1024 rows per wave
    const size_t base = ((size_t)nIdx * S_LEN + sWave) * PITCH
                      + (size_t)hIdx * DDIM;
    const int li = lane >> 4;                  // staging row-in-4 (gload map)
    const int ci = lane & 15;                  // staging col*4
    const float* kl = keys   + base + (size_t)li * PITCH + ci * 4;
    const float* vl = values + base + (size_t)li * PITCH + ci * 4;
    const float* msrc = kmask + (size_t)nIdx * S_LEN + sWave + lane;
    float* maskb = &maskL[wave][0];

    f32x4 acc[4][4];
#pragma unroll
    for (int i = 0; i < 4; ++i)
#pragma unroll
        for (int j = 0; j < 4; ++j) acc[i][j] = f32x4{0.f, 0.f, 0.f, 0.f};
    float zz[4] = {0.f, 0.f, 0.f, 0.f};        // z at d = tj*16 + c16
    unsigned kf[4][4], vf[4][4];               // frags, live across 1 sub-iter

    auto issue = [&](int b, int ch) {          // 8 VMEM (4 K + 4 V)
        const size_t co = (size_t)ch * CH_S * PITCH;
        float* Kd = &Kbuf[wave][0][0] + b * (CH_S * DDIM);
        float* Vd = &Vbuf[wave][0][0] + b * (CH_S * DDIM);
#pragma unroll
        for (int r = 0; r < 4; ++r)
            GLOAD16(Kd + r * 256, kl + co + (size_t)r * 4 * PITCH);
#pragma unroll
        for (int r = 0; r < 4; ++r)
            GLOAD16(Vd + r * 256, vl + co + (size_t)r * 4 * PITCH);
    };

    // transform: lanes with (g>>1)==par build their COMPLETE k=32 frags
    // from this 16-row chunk (rows (g&1)*8..+7); other lanes idle (their
    // frags came from / will come from the sibling-parity chunk).
    auto xform = [&](int b, int ch, int par) {
        if ((g >> 1) == par) {
            const int r0 = (g & 1) * 8;
            const float* Kb = &Kbuf[wave][0][0] + b * (CH_S * DDIM);
            const float* Vb = &Vbuf[wave][0][0] + b * (CH_S * DDIM);
            float mk8[8], kraw[4][8], vraw[4][8];
#pragma unroll
            for (int j = 0; j < 8; ++j) mk8[j] = maskb[ch * CH_S + r0 + j];
#pragma unroll
            for (int tj = 0; tj < 4; ++tj)
#pragma unroll
                for (int j = 0; j < 8; ++j)
                    kraw[tj][j] = Kb[(r0 + j) * DDIM + tj * 16 + c16];
#pragma unroll
            for (int ti = 0; ti < 4; ++ti)
#pragma unroll
                for (int j = 0; j < 8; ++j)
                    vraw[ti][j] = Vb[(r0 + j) * DDIM + ti * 16 + c16];
#pragma unroll
            for (int tj = 0; tj < 4; ++tj)
#pragma unroll
                for (int q = 0; q < 4; ++q) {
                    const float e0 = elup1(kraw[tj][2 * q])     * mk8[2 * q];
                    const float e1 = elup1(kraw[tj][2 * q + 1]) * mk8[2 * q + 1];
                    zz[tj] += e0 + e1;
                    kf[tj][q] = bfpack(e0, e1);
                }
#pragma unroll
            for (int ti = 0; ti < 4; ++ti)
#pragma unroll
                for (int q = 0; q < 4; ++q)
                    vf[ti][q] = bfpack(vraw[ti][2 * q], vraw[ti][2 * q + 1]);
        }
    };

    auto domfma = [&]() {                      // 16 tiles, k=32 (chunk pair)
#pragma unroll
        for (int ti = 0; ti < 4; ++ti) {
            FragCast fa;
            fa.u = uint4v{vf[ti][0], vf[ti][1], vf[ti][2], vf[ti][3]};
#pragma unroll
            for (int tj = 0; tj < 4; ++tj) {
                FragCast fb;
                fb.u = uint4v{kf[tj][0], kf[tj][1], kf[tj][2], kf[tj][3]};
                acc[ti][tj] = __builtin_amdgcn_mfma_f32_16x16x32_bf16(
                    fa.s, fb.s, acc[ti][tj], 0, 0, 0);
            }
        }
    };

    // ---- prologue: all masks (16 GLOAD4) + chunks 0,1,2 (24 VMEM) ----
#pragma unroll
    for (int grp = 0; grp < 16; ++grp)
        GLOAD4(maskb + grp * 64, msrc + grp * 64);
    issue(0, 0);
    issue(1, 1);
    issue(2, 2);

    // ---- main: 4x-unrolled, uniform vmcnt(16), 3 chunks issued ahead ----
#pragma unroll 1
    for (int tt = 0; tt < 15; ++tt) {
        const int c0 = 4 * tt;
        WAITVM(16); issue(3, c0 + 3); xform(0, c0 + 0, 0);
        WAITVM(16); issue(0, c0 + 4); xform(1, c0 + 1, 1); domfma();
        WAITVM(16); issue(1, c0 + 5); xform(2, c0 + 2, 0);
        WAITVM(16); issue(2, c0 + 6); xform(3, c0 + 3, 1); domfma();
    }
    // ---- tail: chunks 60..63 ----
    WAITVM(16); issue(3, 63); xform(0, 60, 0);
    WAITVM(16);               xform(1, 61, 1); domfma();
    WAITVM(8);                xform(2, 62, 0);
    WAITVM(0);                xform(3, 63, 1); domfma();

    // ---- z: sum over the 4 k-groups (lanes xor 16, 32) ----
#pragma unroll
    for (int tj = 0; tj < 4; ++tj) {
        zz[tj] += __shfl_xor(zz[tj], 16, 64);
        zz[tj] += __shfl_xor(zz[tj], 32, 64);
    }

    // ---- per-wave partial -> ws (no block merge, no barriers) ----
    // D-layout [HW-verified m89]: m = ti*16 + g*4 + reg, d = tj*16 + c16
    float* wrow = ws + ((size_t)pair * NWAVE + wave) * WS_ROW;
#pragma unroll
    for (int ti = 0; ti < 4; ++ti)
#pragma unroll
        for (int tj = 0; tj < 4; ++tj)
#pragma unroll
            for (int r = 0; r < 4; ++r)
                wrow[(ti * 16 + g * 4 + r) * 64 + tj * 16 + c16] = acc[ti][tj][r];
    if (g == 0) {
#pragma unroll
        for (int tj = 0; tj < 4; ++tj)
            wrow[64 * 64 + tj * 16 + c16] = zz[tj];
    }
}

// ---------------- reduce + epilogue kernel (r9-proven) ----------------
__global__ __launch_bounds__(256)
void rcla_reduce(const float* __restrict__ query,
                 const float* __restrict__ ws,
                 float* __restrict__ out,
                 int nsplit)
{
    __shared__ float S[64][68];
    __shared__ float zb[64];
    __shared__ float qb[64];

    const int p = blockIdx.x;                  // pair
    const int t = threadIdx.x;
    const float* bp = ws + (size_t)p * nsplit * WS_ROW;

    const int m  = t >> 2;
    const int dc = (t & 3) * 16;
    float4 a[4];
#pragma unroll
    for (int j = 0; j < 4; ++j) a[j] = make_float4(0.f, 0.f, 0.f, 0.f);
    for (int part = 0; part < nsplit; ++part) {
        const float* w = bp + (size_t)part * WS_ROW + m * 64 + dc;
#pragma unroll
        for (int j = 0; j < 4; ++j) {
            const float4 x = *(const float4*)&w[j * 4];
            a[j].x += x.x; a[j].y += x.y; a[j].z += x.z; a[j].w += x.w;
        }
    }
#pragma unroll
    for (int j = 0; j < 4; ++j) {
        *(float4*)&out[OUT_SOFF + (size_t)p * 4096 + m * 64 + dc + j * 4] = a[j];
        *(float4*)&S[m][dc + j * 4] = a[j];
    }
    if (t < 64) {
        float zv = 0.f;
        for (int part = 0; part < nsplit; ++part)
            zv += bp[(size_t)part * WS_ROW + 64 * 64 + t];
        out[OUT_ZOFF + (size_t)p * 64 + t] = zv;
        zb[t] = zv;
        qb[t] = elup1(query[(size_t)p * 64 + t]);
    }
    __syncthreads();

    if (t < 64) {                              // wave 0: V_out
        float zp = qb[t] * zb[t];
#pragma unroll
        for (int off = 32; off >= 1; off >>= 1) zp += __shfl_xor(zp, off, 64);
        const float qz = 1.0f / (zp + 1e-6f);
        float vs = 0.0f;
#pragma unroll
        for (int d = 0; d < 64; d += 4) {
            const float4 sv = *(const float4*)&S[t][d];
            vs = fmaf(qb[d],     sv.x, vs);
            vs = fmaf(qb[d + 1], sv.y, vs);
            vs = fmaf(qb[d + 2], sv.z, vs);
            vs = fmaf(qb[d + 3], sv.w, vs);
        }
        out[(size_t)p * 64 + t] = qz * vs;
    }
}

extern "C" void kernel_launch(void* const* d_in, const int* in_sizes, int n_in,
                              void* d_out, int out_size, void* d_ws, size_t ws_size,
                              hipStream_t stream) {
    const float* q  = (const float*)d_in[0];
    const float* k  = (const float*)d_in[1];
    const float* v  = (const float*)d_in[2];
    const float* km = (const float*)d_in[3];
    float* out = (float*)d_out;
    float* wsf = (float*)d_ws;   // 256*4 partials * 4160 floats = 17.04 MB
                                 // (proven available: r11/r12 ws writes)

    rcla_partial<<<dim3(256), dim3(256), 0, stream>>>(k, v, km, wsf);
    rcla_reduce <<<dim3(256), dim3(256), 0, stream>>>(q, wsf, out, NWAVE);
}

// Round 16
// 111.012 us; speedup vs baseline: 1.2964x; 1.2964x over previous
//
#include <hip/hip_runtime.h>

// RecurrentCrossLinearAttention: N=16, S=4096, H=16, D=64, M=64, fp32.
// Round 16: TLP x MLP. r8 (8 waves, sync) = 103us; r14 (4 waves, async)
// = 106us; both ~5 TB/s combined supply. r14 ran 1 wave/SIMD -> every
// lgkm/VALU stall exposed. This round: 8 waves (2/SIMD, r8-proven shell)
// AND the r14 async counted-vmcnt engine.
//  - per-wave double-buffered 16-row chunks: K+V 8KB x2/wave = 128 KB,
//    mask 4 KB, merge 17.4 KB => ~152 KB (r14-proven size). 9 VMEM/chunk,
//    uniform s_waitcnt vmcnt(9).
//  - FULL-WAVE xform at 16-row granularity, keeping the PROVEN
//    mfma_f32_16x16x32_bf16 via constructive k-permutation: frag u32
//    slots {0,1} <- pair-half 0 rows g*4..g*4+3, slots {2,3} <- half 1.
//    A and B share the k-map => permutation cancels (r7/r8 invariance).
//    No half-wave branches (r15's +38us mistake).
//  - mask staged per-chunk via (lane&15) source: always in-bounds.
// Merge: 8 sequential rmw rounds into mbuf; z/epilogue r14 verbatim.
// launch_bounds (512,1) -> cap 128 (LAW); r8 fit 124 on this compute.
// Canaries: VGPR<=128, WRITE_SIZE ~4.3 MB.

#define S_LEN  4096
#define NHEAD  16
#define DDIM   64
#define MDIM   64
#define NWAVE  8
#define CH_S   16                 // s-rows per chunk; 2 chunks = MFMA k=32
#define NCHK   32                 // chunks per wave: 512/16
#define PITCH  1024               // floats per s row (NHEAD*DDIM)

#define OUT_SOFF  (16 * 16 * 64)
#define OUT_ZOFF  (OUT_SOFF + 16 * 16 * 64 * 64)

using short8 = __attribute__((ext_vector_type(8))) short;
using f32x4  = __attribute__((ext_vector_type(4))) float;
using uint4v = __attribute__((ext_vector_type(4))) unsigned int;

union FragCast { uint4v u; short8 s; };

typedef const __attribute__((address_space(1))) void gvoid_t;
typedef __attribute__((address_space(3))) void lvoid_t;

#define GLOAD16(dst, src) \
    __builtin_amdgcn_global_load_lds((gvoid_t*)(src), (lvoid_t*)(dst), 16, 0, 0)
#define GLOAD4(dst, src) \
    __builtin_amdgcn_global_load_lds((gvoid_t*)(src), (lvoid_t*)(dst), 4, 0, 0)
#define WAITVM(N) do { asm volatile("s_waitcnt vmcnt(" #N ")" ::: "memory"); \
                       __builtin_amdgcn_sched_barrier(0); } while (0)

__device__ __forceinline__ float elup1(float x) {
    // elu(x) + 1 = x+1 (x>0) else exp(x)
    return x > 0.0f ? x + 1.0f : __expf(x);
}

// pack two fp32 -> {lo=bf16(a), hi=bf16(b)} with round-to-nearest-even
__device__ __forceinline__ unsigned bfpack(float a, float b) {
    union { float f; unsigned u; } ca, cb;
    ca.f = a; cb.f = b;
    const unsigned ra = ca.u + 0x7FFFu + ((ca.u >> 16) & 1u);
    const unsigned rb = cb.u + 0x7FFFu + ((cb.u >> 16) & 1u);
    return (ra >> 16) | (rb & 0xFFFF0000u);
}

__global__ __launch_bounds__(512, 1)
void rcla_fused(const float* __restrict__ query,
                const float* __restrict__ keys,
                const float* __restrict__ values,
                const float* __restrict__ kmask,
                float* __restrict__ out)
{
    __shared__ float Kbuf[NWAVE][2][CH_S * DDIM];  // 64 KB
    __shared__ float Vbuf[NWAVE][2][CH_S * DDIM];  // 64 KB
    __shared__ float mkb[NWAVE][2][64];            // 4 KB (16 valid + dup)
    __shared__ float mbuf[64][68];                 // 17.4 KB merge / S
    __shared__ float zrows[NWAVE][64];             // 2 KB
    __shared__ float qb[64];
    __shared__ float zb[64];

    const int t    = threadIdx.x;
    const int wave = t >> 6;                   // 0..7
    const int lane = t & 63;
    const int c16  = lane & 15;                // free index (m for A, d for B)
    const int g    = lane >> 4;                // row-group 0..3 (4 rows each)
    const int pair = blockIdx.x;               // n*16 + h
    const int nIdx = pair >> 4;
    const int hIdx = pair & 15;

    const int sWave = wave * (NCHK * CH_S);    // 512 rows per wave
    const size_t base = ((size_t)nIdx * S_LEN + sWave) * PITCH
                      + (size_t)hIdx * DDIM;
    // staging lane map (r14-proven): instr r covers rows r*4..r*4+3;
    // lane -> row r*4 + (lane>>4), cols (lane&15)*4.. (lane-contig 16B)
    const int li = lane >> 4;
    const int ci = lane & 15;
    const float* kl = keys   + base + (size_t)li * PITCH + ci * 4;
    const float* vl = values + base + (size_t)li * PITCH + ci * 4;
    const float* ml = kmask + (size_t)nIdx * S_LEN + sWave + (lane & 15);

    f32x4 acc[4][4];
#pragma unroll
    for (int i = 0; i < 4; ++i)
#pragma unroll
        for (int j = 0; j < 4; ++j) acc[i][j] = f32x4{0.f, 0.f, 0.f, 0.f};
    float zz[4] = {0.f, 0.f, 0.f, 0.f};        // z at d = tj*16 + c16
    unsigned kf[4][4], vf[4][4];               // frags, filled half per chunk

    auto issue = [&](int b, int ch) {          // 9 VMEM (4 K + 4 V + 1 mask)
        const size_t co = (size_t)ch * CH_S * PITCH;
        float* Kd = &Kbuf[wave][0][0] + b * (CH_S * DDIM);
        float* Vd = &Vbuf[wave][0][0] + b * (CH_S * DDIM);
#pragma unroll
        for (int r = 0; r < 4; ++r)
            GLOAD16(Kd + r * 256, kl + co + (size_t)r * 4 * PITCH);
#pragma unroll
        for (int r = 0; r < 4; ++r)
            GLOAD16(Vd + r * 256, vl + co + (size_t)r * 4 * PITCH);
        GLOAD4(&mkb[wave][b][0], ml + ch * CH_S);
    };

    // full-wave transform of one 16-row chunk into frag half `hf`:
    // lane reads rows g*4..g*4+3, cols {tj|ti}*16+c16; fills u32 slots
    // 2*hf, 2*hf+1 of kf/vf. k-permutation shared by A and B -> cancels.
    auto xform = [&](int b, int hf) {
        const float* Kb = &Kbuf[wave][0][0] + b * (CH_S * DDIM);
        const float* Vb = &Vbuf[wave][0][0] + b * (CH_S * DDIM);
        const float* mk = &mkb[wave][b][0];
        float m4[4];
#pragma unroll
        for (int j = 0; j < 4; ++j) m4[j] = mk[g * 4 + j];
#pragma unroll
        for (int tj = 0; tj < 4; ++tj) {
            float kr[4];
#pragma unroll
            for (int j = 0; j < 4; ++j)
                kr[j] = Kb[(g * 4 + j) * DDIM + tj * 16 + c16];
            const float e0 = elup1(kr[0]) * m4[0];
            const float e1 = elup1(kr[1]) * m4[1];
            const float e2 = elup1(kr[2]) * m4[2];
            const float e3 = elup1(kr[3]) * m4[3];
            zz[tj] += (e0 + e1) + (e2 + e3);
            kf[tj][2 * hf]     = bfpack(e0, e1);
            kf[tj][2 * hf + 1] = bfpack(e2, e3);
        }
#pragma unroll
        for (int ti = 0; ti < 4; ++ti) {
            float vr[4];
#pragma unroll
            for (int j = 0; j < 4; ++j)
                vr[j] = Vb[(g * 4 + j) * DDIM + ti * 16 + c16];
            vf[ti][2 * hf]     = bfpack(vr[0], vr[1]);
            vf[ti][2 * hf + 1] = bfpack(vr[2], vr[3]);
        }
    };

    auto domfma = [&]() {                      // 16 tiles, k=32 (chunk pair)
#pragma unroll
        for (int ti = 0; ti < 4; ++ti) {
            FragCast fa;
            fa.u = uint4v{vf[ti][0], vf[ti][1], vf[ti][2], vf[ti][3]};
#pragma unroll
            for (int tj = 0; tj < 4; ++tj) {
                FragCast fb;
                fb.u = uint4v{kf[tj][0], kf[tj][1], kf[tj][2], kf[tj][3]};
                acc[ti][tj] = __builtin_amdgcn_mfma_f32_16x16x32_bf16(
                    fa.s, fb.s, acc[ti][tj], 0, 0, 0);
            }
        }
    };

    // ---- counted-vmcnt double-buffered stream (r14-proven peel) ----
    issue(0, 0);
#pragma unroll 1
    for (int c = 0; c < NCHK - 2; c += 2) {
        issue(1, c + 1);
        WAITVM(9);                 // chunk c resident (c+1's 9 in flight)
        xform(0, 0);
        issue(0, c + 2);
        WAITVM(9);                 // chunk c+1 resident (c+2's in flight)
        xform(1, 1);
        domfma();
    }
    issue(1, NCHK - 1);
    WAITVM(9);
    xform(0, 0);                   // chunk 30
    WAITVM(0);
    xform(1, 1);                   // chunk 31
    domfma();

    // ---- z: sum over the 4 row-groups (lanes xor 16, 32) ----
#pragma unroll
    for (int tj = 0; tj < 4; ++tj) {
        zz[tj] += __shfl_xor(zz[tj], 16, 64);
        zz[tj] += __shfl_xor(zz[tj], 32, 64);
    }

    __syncthreads();               // all waves done streaming

    // ---- S merge: 8 sequential barriered rmw rounds ----
    // D-layout [HW-verified m89]: m = ti*16 + g*4 + reg, d = tj*16 + c16
    for (int rr = 0; rr < NWAVE; ++rr) {
        if (wave == rr) {
#pragma unroll
            for (int ti = 0; ti < 4; ++ti)
#pragma unroll
                for (int tj = 0; tj < 4; ++tj)
#pragma unroll
                    for (int r = 0; r < 4; ++r) {
                        const int m = ti * 16 + g * 4 + r;
                        const int d = tj * 16 + c16;
                        if (rr == 0) mbuf[m][d]  = acc[ti][tj][r];
                        else         mbuf[m][d] += acc[ti][tj][r];
                    }
        }
        __syncthreads();
    }

    // ---- z rows (write-only, disjoint) + q load ----
    if (g == 0) {
#pragma unroll
        for (int tj = 0; tj < 4; ++tj)
            zrows[wave][tj * 16 + c16] = zz[tj];
    }
    if (t < 64) qb[t] = elup1(query[(size_t)pair * DDIM + t]);

    // ---- S -> out ----
    {
        const int m  = t >> 3;
        const int dc = (t & 7) * 8;
#pragma unroll
        for (int j = 0; j < 8; j += 4)
            *(float4*)&out[OUT_SOFF + (size_t)pair * 4096 + m * 64 + dc + j] =
                *(const float4*)&mbuf[m][dc + j];
    }
    __syncthreads();

    if (t < 64) {
        float zv = 0.f;
#pragma unroll
        for (int r = 0; r < NWAVE; ++r) zv += zrows[r][t];
        out[OUT_ZOFF + (size_t)pair * 64 + t] = zv;
        zb[t] = zv;
    }
    __syncthreads();

    // ---- epilogue: wave 0, lane = m (r8-proven) ----
    if (wave == 0) {
        float zp = qb[lane] * zb[lane];
#pragma unroll
        for (int off = 32; off >= 1; off >>= 1) zp += __shfl_xor(zp, off, 64);
        const float qz = 1.0f / (zp + 1e-6f);
        float vs = 0.0f;
#pragma unroll
        for (int d = 0; d < 64; d += 4) {
            const float4 sv = *(const float4*)&mbuf[lane][d];
            vs = fmaf(qb[d],     sv.x, vs);
            vs = fmaf(qb[d + 1], sv.y, vs);
            vs = fmaf(qb[d + 2], sv.z, vs);
            vs = fmaf(qb[d + 3], sv.w, vs);
        }
        out[(size_t)pair * MDIM + lane] = qz * vs;
    }
}

extern "C" void kernel_launch(void* const* d_in, const int* in_sizes, int n_in,
                              void* d_out, int out_size, void* d_ws, size_t ws_size,
                              hipStream_t stream) {
    const float* q  = (const float*)d_in[0];
    const float* k  = (const float*)d_in[1];
    const float* v  = (const float*)d_in[2];
    const float* km = (const float*)d_in[3];
    float* out = (float*)d_out;
    rcla_fused<<<dim3(256), dim3(512), 0, stream>>>(q, k, v, km, out);
}